// Round 9
// baseline (234.936 us; speedup 1.0000x reference)
//
#include <hip/hip_runtime.h>
#include <math.h>

#define NN 4096
#define CC 256

typedef unsigned short u16;
typedef unsigned int u32;
typedef float f32x16 __attribute__((ext_vector_type(16)));
typedef short s16x8 __attribute__((ext_vector_type(8)));

#define ZERO16 {0.f,0.f,0.f,0.f,0.f,0.f,0.f,0.f,0.f,0.f,0.f,0.f,0.f,0.f,0.f,0.f}
#define LOG2E 1.4426950408889634f

__device__ __forceinline__ u16 f2bf(float f){
    unsigned u = __float_as_uint(f);
    return (u16)((u + 0x7fffu + ((u >> 16) & 1u)) >> 16);
}
__device__ __forceinline__ float bf2f(u16 h){
    return __uint_as_float(((unsigned)h) << 16);
}

// ---------------------------------------------------------------- gate + W prep
__global__ __launch_bounds__(256) void gate_kernel(
    const float* __restrict__ g0, const float* __restrict__ Wq,
    const float* __restrict__ Wk, const float* __restrict__ Wv,
    float* __restrict__ gate,
    u16* __restrict__ wqhi, u16* __restrict__ wqlo,
    u16* __restrict__ wkhi, u16* __restrict__ wklo,
    u16* __restrict__ wvbf)
{
    int idx = blockIdx.x * 256 + threadIdx.x;      // 0..16383
    int b  = idx >> 12;
    int hw = idx & 4095;
    int h = hw >> 6, w = hw & 63;
    float ys = h * (31.0f / 63.0f);
    float xs = w * (31.0f / 63.0f);
    int y0 = (int)ys, x0 = (int)xs;
    int y1 = min(y0 + 1, 31), x1 = min(x0 + 1, 31);
    float wy = ys - (float)y0, wx = xs - (float)x0;
    const float* g = g0 + b * 1024;
    float g00 = g[y0 * 32 + x0], g01 = g[y0 * 32 + x1];
    float g10 = g[y1 * 32 + x0], g11 = g[y1 * 32 + x1];
    float top = g00 * (1.0f - wx) + g01 * wx;
    float bot = g10 * (1.0f - wx) + g11 * wx;
    float val = top * (1.0f - wy) + bot * wy;
    gate[idx] = 1.0f + 1.0f / (1.0f + __expf(-val));

    if (idx < 8192) {
        float a = Wq[idx];
        u16 ha = f2bf(a);
        wqhi[idx] = ha; wqlo[idx] = f2bf(a - bf2f(ha));
        float c = Wk[idx];
        u16 hc = f2bf(c);
        wkhi[idx] = hc; wklo[idx] = f2bf(c - bf2f(hc));
    }
#pragma unroll
    for (int j = 0; j < 4; j++)
        wvbf[idx + j * 16384] = f2bf(Wv[idx + j * 16384]);
}

// ---------------------------------------------------------------- qkv -----
// 256 blocks (b, nt of 64 n). x staged once in LDS as bf16 hi/lo [n][c] swizzled.
// 8 waves: 0..3 = q/k (proj, nhalf) hi/lo-split MFMA; 4..7 = v (64 c each).
// q/k written PACKED: row [n][hi0..hi31 | lo0..lo31] (128 B per n).
// q is pre-scaled by log2(e) so downstream softmax runs in exp2 domain.
__global__ __launch_bounds__(512, 4) void qkv_kernel(
    const float* __restrict__ x,
    const u16* __restrict__ wqhi, const u16* __restrict__ wqlo,
    const u16* __restrict__ wkhi, const u16* __restrict__ wklo,
    const u16* __restrict__ wvbf,
    const float* __restrict__ bq, const float* __restrict__ bk,
    const float* __restrict__ bv, const float* __restrict__ gate,
    u16* __restrict__ qpk, u16* __restrict__ kpk,
    u16* __restrict__ vbf)
{
    __shared__ u16 Xh[64 * 256];   // [n][c] swizzled, 32 KB
    __shared__ u16 Xl[64 * 256];   // 32 KB
    int bid = blockIdx.x;
    int b  = (bid >> 1) & 3;
    int nt = (bid >> 3) | ((bid & 1) << 5);
    int n0 = nt * 64;
    int tid = threadIdx.x;

    // ---- stage x -> LDS (hi/lo bf16, [n][c], XOR-swizzled rows)
    {
        const float* xb = x + (size_t)b * CC * NN;
        int cb = tid >> 4;          // 0..31
        int nc = tid & 15;          // 4-n chunk
#pragma unroll
        for (int j = 0; j < 8; j++) {
            int c = cb + 32 * j;
            float4 xv = *(const float4*)(xb + (size_t)c * NN + n0 + nc * 4);
            float xf[4] = {xv.x, xv.y, xv.z, xv.w};
#pragma unroll
            for (int i = 0; i < 4; i++) {
                int n = nc * 4 + i;
                u16 hv = f2bf(xf[i]);
                u16 lv = f2bf(xf[i] - bf2f(hv));
                int u = n * 256 + (c ^ ((n & 31) << 3));
                Xh[u] = hv; Xl[u] = lv;
            }
        }
    }
    __syncthreads();

    int w = tid >> 6, l = tid & 63;
    int l5 = l >> 5, l31 = l & 31;

    if (w < 4) {
        // ---- q,k
        int proj = w & 1, nh = w >> 1;
        const u16* Whi = proj ? wkhi : wqhi;
        const u16* Wlo = proj ? wklo : wqlo;
        const float* bias = proj ? bk : bq;
        u16* dpk = proj ? kpk : qpk;
        float scale = proj ? 1.0f : LOG2E;
        int nl = nh * 32 + l31;
        int swz = (nl & 31) << 3;

        f32x16 acc = ZERO16;
        for (int ks = 0; ks < 16; ks++) {
            int c0 = ks * 16 + 8 * l5;
            s16x8 whi = *(const s16x8*)(Whi + l31 * 256 + c0);
            s16x8 wlo = *(const s16x8*)(Wlo + l31 * 256 + c0);
            int u = nl * 256 + (c0 ^ swz);
            s16x8 xh = *(const s16x8*)(Xh + u);
            s16x8 xl = *(const s16x8*)(Xl + u);
            acc = __builtin_amdgcn_mfma_f32_32x32x16_bf16(whi, xh, acc, 0, 0, 0);
            acc = __builtin_amdgcn_mfma_f32_32x32x16_bf16(whi, xl, acc, 0, 0, 0);
            acc = __builtin_amdgcn_mfma_f32_32x32x16_bf16(wlo, xh, acc, 0, 0, 0);
        }
        int n = n0 + nl;
        float g = gate[b * NN + n] * scale;
        size_t rowo = ((size_t)b * NN + n) * 64;
#pragma unroll
        for (int t = 0; t < 4; t++) {
            int ob = 8 * t + 4 * l5;
            unsigned h01 = 0, h23 = 0, l01 = 0, l23 = 0;
#pragma unroll
            for (int j = 0; j < 4; j++) {
                float v = (acc[4 * t + j] + bias[ob + j]) * g;
                u16 h = f2bf(v);
                u16 lo = f2bf(v - bf2f(h));
                if (j < 2) { h01 |= ((unsigned)h) << (16 * j); l01 |= ((unsigned)lo) << (16 * j); }
                else       { h23 |= ((unsigned)h) << (16 * (j - 2)); l23 |= ((unsigned)lo) << (16 * (j - 2)); }
            }
            *(unsigned*)(dpk + rowo + ob)          = h01;
            *(unsigned*)(dpk + rowo + ob + 2)      = h23;
            *(unsigned*)(dpk + rowo + 32 + ob)     = l01;
            *(unsigned*)(dpk + rowo + 32 + ob + 2) = l23;
        }
    } else {
        // ---- v: wave covers 64 c x 64 n
        int vw = w - 4;
        int cB = vw * 64;
        int swz = (l31 & 31) << 3;
        f32x16 acc[2][2] = {{ZERO16, ZERO16}, {ZERO16, ZERO16}};
        for (int ks = 0; ks < 16; ks++) {
            int c0 = ks * 16 + 8 * l5;
            int u0 = l31 * 256 + (c0 ^ swz);
            s16x8 xh0 = *(const s16x8*)(Xh + u0);
            s16x8 xh1 = *(const s16x8*)(Xh + u0 + 32 * 256);
#pragma unroll
            for (int ct = 0; ct < 2; ct++) {
                s16x8 wv = *(const s16x8*)(wvbf + (size_t)(cB + ct * 32 + l31) * 256 + c0);
                acc[ct][0] = __builtin_amdgcn_mfma_f32_32x32x16_bf16(wv, xh0, acc[ct][0], 0, 0, 0);
                acc[ct][1] = __builtin_amdgcn_mfma_f32_32x32x16_bf16(wv, xh1, acc[ct][1], 0, 0, 0);
            }
        }
#pragma unroll
        for (int nh2 = 0; nh2 < 2; nh2++) {
            int n = n0 + nh2 * 32 + l31;
            float g = gate[b * NN + n];
#pragma unroll
            for (int ct = 0; ct < 2; ct++) {
#pragma unroll
                for (int r = 0; r < 16; r++) {
                    int c = cB + ct * 32 + (r & 3) + 8 * (r >> 2) + 4 * l5;
                    vbf[((size_t)b * CC + c) * NN + n] = f2bf((acc[ct][nh2][r] + bv[c]) * g);
                }
            }
        }
    }
}

// ---------------------------------------------------------------- stats ---
// 256 blocks x 8 waves (strip=w&1, ns=w>>1). SWAPPED energy: S^T = mfma(K,Q)
// -> lane = m, regs = n. Per-lane scalar online stats; lse in log2 domain.
__global__ __launch_bounds__(512, 4) void stats_kernel(
    const u16* __restrict__ qpk, const u16* __restrict__ kpk,
    float* __restrict__ lse)
{
    __shared__ float Sm[8][32], Ss[8][32];
    int bid = blockIdx.x;
    int b  = (bid >> 1) & 3;
    int mt = (bid >> 3) | ((bid & 1) << 5);
    int tid = threadIdx.x;
    int w = tid >> 6, l = tid & 63;
    int l5 = l >> 5, l31 = l & 31;
    int strip = w & 1, ns = w >> 1;
    int mS = mt * 64 + strip * 32;

    size_t qo = ((size_t)b * NN + mS + l31) * 64 + 8 * l5;
    s16x8 qh0 = *(const s16x8*)(qpk + qo),      ql0 = *(const s16x8*)(qpk + qo + 32);
    s16x8 qh1 = *(const s16x8*)(qpk + qo + 16), ql1 = *(const s16x8*)(qpk + qo + 48);

    float rmax = -1e30f, rsum = 0.f;

    for (int it = 0; it < 32; it++) {
        size_t ko = ((size_t)b * NN + it * 128 + ns * 32 + l31) * 64 + 8 * l5;
        s16x8 kh0 = *(const s16x8*)(kpk + ko),      kl0 = *(const s16x8*)(kpk + ko + 32);
        s16x8 kh1 = *(const s16x8*)(kpk + ko + 16), kl1 = *(const s16x8*)(kpk + ko + 48);
        f32x16 a = ZERO16;
        a = __builtin_amdgcn_mfma_f32_32x32x16_bf16(kh0, ql0, a, 0, 0, 0);
        a = __builtin_amdgcn_mfma_f32_32x32x16_bf16(kl0, qh0, a, 0, 0, 0);
        a = __builtin_amdgcn_mfma_f32_32x32x16_bf16(kh0, qh0, a, 0, 0, 0);
        a = __builtin_amdgcn_mfma_f32_32x32x16_bf16(kh1, ql1, a, 0, 0, 0);
        a = __builtin_amdgcn_mfma_f32_32x32x16_bf16(kl1, qh1, a, 0, 0, 0);
        a = __builtin_amdgcn_mfma_f32_32x32x16_bf16(kh1, qh1, a, 0, 0, 0);
        // per-lane (m fixed): 16 n-values on regs
        float t0 = fmaxf(fmaxf(a[0], a[1]),   fmaxf(a[2], a[3]));
        float t1 = fmaxf(fmaxf(a[4], a[5]),   fmaxf(a[6], a[7]));
        float t2 = fmaxf(fmaxf(a[8], a[9]),   fmaxf(a[10], a[11]));
        float t3 = fmaxf(fmaxf(a[12], a[13]), fmaxf(a[14], a[15]));
        float tm = fmaxf(fmaxf(t0, t1), fmaxf(t2, t3));
        float nm = fmaxf(rmax, tm);
        float add = 0.f;
#pragma unroll
        for (int r = 0; r < 16; r++) add += exp2f(a[r] - nm);
        rsum = rsum * exp2f(rmax - nm) + add;
        rmax = nm;
    }

    // merge the two l5 halves (same m, disjoint n)
    {
        float om = __shfl_xor(rmax, 32);
        float os = __shfl_xor(rsum, 32);
        float nm = fmaxf(rmax, om);
        rsum = rsum * exp2f(rmax - nm) + os * exp2f(om - nm);
        rmax = nm;
    }
    if (l < 32) { Sm[w][l] = rmax; Ss[w][l] = rsum; }
    __syncthreads();
    if (tid < 64) {
        int ww = tid >> 5;         // strip
        int mm = tid & 31;
        float M = -1e30f;
#pragma unroll
        for (int j = 0; j < 4; j++) M = fmaxf(M, Sm[ww + 2 * j][mm]);
        float S = 0.f;
#pragma unroll
        for (int j = 0; j < 4; j++)
            S += Ss[ww + 2 * j][mm] * exp2f(Sm[ww + 2 * j][mm] - M);
        lse[b * NN + mt * 64 + ww * 32 + mm] = M + log2f(S);
    }
}

// ---------------------------------------------------------------- out -----
// 512 blocks: sub=bid&7 -> b=sub>>1, ch=sub&1; mt=bid>>3. 64m x 128c.
// 8 waves = (strip=w&1, cq=w>>1). Swapped energy (lane=m), P packed b64
// writes into double-buffered LDS; V direct from global (contiguous per
// lane over the iter); ONE barrier per iter (ENERGY(it+1) || PV(it)).
__global__ __launch_bounds__(512, 2) void out_kernel(
    const u16* __restrict__ qpk, const u16* __restrict__ kpk,
    const u16* __restrict__ vbf, const float* __restrict__ lse,
    const float* __restrict__ x, const float* __restrict__ gamma,
    float* __restrict__ out)
{
    __shared__ u16 Pl[2][64 * 128];   // [m][n] swizzled, 16 KB each
    int bid = blockIdx.x;
    int sub = bid & 7;
    int b  = sub >> 1;
    int ch = sub & 1;
    int mt = bid >> 3;
    int tid = threadIdx.x;
    int w = tid >> 6, l = tid & 63;
    int l5 = l >> 5, l31 = l & 31;
    int strip = w & 1, cq = w >> 1;
    int mS = mt * 64 + strip * 32;

    size_t qo = ((size_t)b * NN + mS + l31) * 64 + 8 * l5;
    s16x8 qh0 = *(const s16x8*)(qpk + qo),      ql0 = *(const s16x8*)(qpk + qo + 32);
    s16x8 qh1 = *(const s16x8*)(qpk + qo + 16), ql1 = *(const s16x8*)(qpk + qo + 48);

    float lse_m = lse[b * NN + mS + l31];      // scalar per lane (log2 domain)

    f32x16 acc = ZERO16;
    const u16* vrow = vbf + ((size_t)b * CC + ch * 128 + cq * 32 + l31) * NN + 8 * l5;

    int mloc = strip * 32 + l31;               // P row [0..63]
    int wbase = mloc * 256;                    // byte offset of row (128 n x 2B)
    int wswz  = (mloc & 15) << 4;              // XOR swizzle (16B granule)

    auto ENERGY = [&](int it) {
        int n0 = it * 128;
        size_t ko = ((size_t)b * NN + n0 + cq * 32 + l31) * 64 + 8 * l5;
        s16x8 kh0 = *(const s16x8*)(kpk + ko),      kl0 = *(const s16x8*)(kpk + ko + 32);
        s16x8 kh1 = *(const s16x8*)(kpk + ko + 16), kl1 = *(const s16x8*)(kpk + ko + 48);
        f32x16 a = ZERO16;
        a = __builtin_amdgcn_mfma_f32_32x32x16_bf16(kh0, ql0, a, 0, 0, 0);
        a = __builtin_amdgcn_mfma_f32_32x32x16_bf16(kl0, qh0, a, 0, 0, 0);
        a = __builtin_amdgcn_mfma_f32_32x32x16_bf16(kh0, qh0, a, 0, 0, 0);
        a = __builtin_amdgcn_mfma_f32_32x32x16_bf16(kh1, ql1, a, 0, 0, 0);
        a = __builtin_amdgcn_mfma_f32_32x32x16_bf16(kl1, qh1, a, 0, 0, 0);
        a = __builtin_amdgcn_mfma_f32_32x32x16_bf16(kh1, qh1, a, 0, 0, 0);
        char* Pb = (char*)Pl[it & 1];
#pragma unroll
        for (int g = 0; g < 4; g++) {
            // n = cq*32 + 8g + 4*l5 + (0..3)  -> 4 consecutive bf16 = one b64
            u16 p0 = f2bf(exp2f(a[4 * g + 0] - lse_m));
            u16 p1 = f2bf(exp2f(a[4 * g + 1] - lse_m));
            u16 p2 = f2bf(exp2f(a[4 * g + 2] - lse_m));
            u16 p3 = f2bf(exp2f(a[4 * g + 3] - lse_m));
            uint2 pk;
            pk.x = (u32)p0 | ((u32)p1 << 16);
            pk.y = (u32)p2 | ((u32)p3 << 16);
            int nb = cq * 64 + 16 * g + 8 * l5;            // byte offset of n
            *(uint2*)(Pb + ((wbase + nb) ^ wswz)) = pk;
        }
    };

    auto PV = [&](int it) {
        const char* Pb = (const char*)Pl[it & 1];
        int n0 = it * 128;
#pragma unroll
        for (int ks = 0; ks < 8; ks++) {
            int cb = ks * 32 + 16 * l5;                    // byte col
            s16x8 pa = *(const s16x8*)(Pb + ((wbase + cb) ^ wswz));
            s16x8 vv = *(const s16x8*)(vrow + n0 + ks * 16);
            acc = __builtin_amdgcn_mfma_f32_32x32x16_bf16(pa, vv, acc, 0, 0, 0);
        }
    };

    ENERGY(0);
    __syncthreads();
#pragma unroll 2
    for (int it = 0; it < 31; it++) {
        ENERGY(it + 1);
        PV(it);
        __syncthreads();
    }
    PV(31);

    float gm = gamma[0];
    int c = ch * 128 + cq * 32 + l31;
#pragma unroll
    for (int t = 0; t < 4; t++) {
        size_t o = ((size_t)b * CC + c) * NN + mS + 8 * t + 4 * l5;
        float4 x4 = *(const float4*)(x + o);
        float4 r4;
        r4.x = fmaf(gm, acc[4 * t + 0], x4.x);
        r4.y = fmaf(gm, acc[4 * t + 1], x4.y);
        r4.z = fmaf(gm, acc[4 * t + 2], x4.z);
        r4.w = fmaf(gm, acc[4 * t + 3], x4.w);
        *(float4*)(out + o) = r4;
    }
}

// ---------------------------------------------------------------- launch --
extern "C" void kernel_launch(void* const* d_in, const int* in_sizes, int n_in,
                              void* d_out, int out_size, void* d_ws, size_t ws_size,
                              hipStream_t stream)
{
    const float* x     = (const float*)d_in[0];
    const float* g0    = (const float*)d_in[1];
    const float* Wq    = (const float*)d_in[2];
    const float* bq    = (const float*)d_in[3];
    const float* Wk    = (const float*)d_in[4];
    const float* bk    = (const float*)d_in[5];
    const float* Wv    = (const float*)d_in[6];
    const float* bv    = (const float*)d_in[7];
    const float* gamma = (const float*)d_in[8];
    float* out = (float*)d_out;

    char* p = (char*)d_ws;
    u16* qpk = (u16*)p; p += (size_t)4 * NN * 64 * 2;   // 2 MB packed [n][hi|lo]
    u16* kpk = (u16*)p; p += (size_t)4 * NN * 64 * 2;   // 2 MB
    u16* vbf = (u16*)p; p += (size_t)4 * CC * NN * 2;   // 8 MB
    float* gate = (float*)p; p += (size_t)4 * NN * 4;
    float* lse  = (float*)p; p += (size_t)4 * NN * 4;
    u16* wqhi = (u16*)p; p += 8192 * 2;
    u16* wqlo = (u16*)p; p += 8192 * 2;
    u16* wkhi = (u16*)p; p += 8192 * 2;
    u16* wklo = (u16*)p; p += 8192 * 2;
    u16* wvbf = (u16*)p; p += 65536 * 2;

    hipLaunchKernelGGL(gate_kernel, dim3(64), dim3(256), 0, stream,
                       g0, Wq, Wk, Wv, gate, wqhi, wqlo, wkhi, wklo, wvbf);
    hipLaunchKernelGGL(qkv_kernel, dim3(256), dim3(512), 0, stream,
                       x, wqhi, wqlo, wkhi, wklo, wvbf, bq, bk, bv, gate,
                       qpk, kpk, vbf);
    hipLaunchKernelGGL(stats_kernel, dim3(256), dim3(512), 0, stream,
                       qpk, kpk, lse);
    hipLaunchKernelGGL(out_kernel, dim3(512), dim3(512), 0, stream,
                       qpk, kpk, vbf, lse, x, gamma, out);
}

// Round 10
// 192.601 us; speedup vs baseline: 1.2198x; 1.2198x over previous
//
#include <hip/hip_runtime.h>
#include <math.h>

#define NN 4096
#define CC 256

typedef unsigned short u16;
typedef unsigned int u32;
typedef float f32x16 __attribute__((ext_vector_type(16)));
typedef short s16x8 __attribute__((ext_vector_type(8)));

#define ZERO16 {0.f,0.f,0.f,0.f,0.f,0.f,0.f,0.f,0.f,0.f,0.f,0.f,0.f,0.f,0.f,0.f}
#define LOG2E 1.4426950408889634f

#define GLOAD_LDS16(gsrc, ldst) \
    __builtin_amdgcn_global_load_lds((const __attribute__((address_space(1))) unsigned int*)(gsrc), \
                                     (__attribute__((address_space(3))) unsigned int*)(ldst), 16, 0, 0)

__device__ __forceinline__ u16 f2bf(float f){
    unsigned u = __float_as_uint(f);
    return (u16)((u + 0x7fffu + ((u >> 16) & 1u)) >> 16);
}
__device__ __forceinline__ float bf2f(u16 h){
    return __uint_as_float(((unsigned)h) << 16);
}
__device__ __forceinline__ u32 cvtpk_bf16(float a, float b){
    u32 r;
    asm("v_cvt_pk_bf16_f32 %0, %1, %2" : "=v"(r) : "v"(a), "v"(b));
    return r;
}
// n-index involution: swap bits 2 and 3 (V stored in "logical" order so PV
// A-fragments are lane-local cvt_pk of consecutive S registers)
__device__ __forceinline__ int nswap23(int n){
    return (n & ~12) | ((n & 4) << 1) | ((n & 8) >> 1);
}

// ---------------------------------------------------------------- gate + W prep
__global__ __launch_bounds__(256) void gate_kernel(
    const float* __restrict__ g0, const float* __restrict__ Wq,
    const float* __restrict__ Wk, const float* __restrict__ Wv,
    float* __restrict__ gate,
    u16* __restrict__ wqhi, u16* __restrict__ wqlo,
    u16* __restrict__ wkhi, u16* __restrict__ wklo,
    u16* __restrict__ wvbf)
{
    int idx = blockIdx.x * 256 + threadIdx.x;      // 0..16383
    int b  = idx >> 12;
    int hw = idx & 4095;
    int h = hw >> 6, w = hw & 63;
    float ys = h * (31.0f / 63.0f);
    float xs = w * (31.0f / 63.0f);
    int y0 = (int)ys, x0 = (int)xs;
    int y1 = min(y0 + 1, 31), x1 = min(x0 + 1, 31);
    float wy = ys - (float)y0, wx = xs - (float)x0;
    const float* g = g0 + b * 1024;
    float g00 = g[y0 * 32 + x0], g01 = g[y0 * 32 + x1];
    float g10 = g[y1 * 32 + x0], g11 = g[y1 * 32 + x1];
    float top = g00 * (1.0f - wx) + g01 * wx;
    float bot = g10 * (1.0f - wx) + g11 * wx;
    float val = top * (1.0f - wy) + bot * wy;
    gate[idx] = 1.0f + 1.0f / (1.0f + __expf(-val));

    if (idx < 8192) {
        float a = Wq[idx];
        u16 ha = f2bf(a);
        wqhi[idx] = ha; wqlo[idx] = f2bf(a - bf2f(ha));
        float c = Wk[idx];
        u16 hc = f2bf(c);
        wkhi[idx] = hc; wklo[idx] = f2bf(c - bf2f(hc));
    }
#pragma unroll
    for (int j = 0; j < 4; j++)
        wvbf[idx + j * 16384] = f2bf(Wv[idx + j * 16384]);
}

// ---------------------------------------------------------------- qkv -----
// 256 blocks (b, nt of 64 n). x staged once in LDS as bf16 hi/lo [n][c] swizzled.
// 8 waves: 0..3 = q/k (hi/lo split, PACKED rows [n][hi|lo], q pre-scaled by
// log2e); 4..7 = v -> bf16 [b][c][n'] with n' = nswap23(n).
__global__ __launch_bounds__(512, 4) void qkv_kernel(
    const float* __restrict__ x,
    const u16* __restrict__ wqhi, const u16* __restrict__ wqlo,
    const u16* __restrict__ wkhi, const u16* __restrict__ wklo,
    const u16* __restrict__ wvbf,
    const float* __restrict__ bq, const float* __restrict__ bk,
    const float* __restrict__ bv, const float* __restrict__ gate,
    u16* __restrict__ qpk, u16* __restrict__ kpk,
    u16* __restrict__ vbf)
{
    __shared__ u16 Xh[64 * 256];   // [n][c] swizzled, 32 KB
    __shared__ u16 Xl[64 * 256];   // 32 KB
    int bid = blockIdx.x;
    int b  = (bid >> 1) & 3;
    int nt = (bid >> 3) | ((bid & 1) << 5);
    int n0 = nt * 64;
    int tid = threadIdx.x;

    {
        const float* xb = x + (size_t)b * CC * NN;
        int cb = tid >> 4;
        int nc = tid & 15;
#pragma unroll
        for (int j = 0; j < 8; j++) {
            int c = cb + 32 * j;
            float4 xv = *(const float4*)(xb + (size_t)c * NN + n0 + nc * 4);
            float xf[4] = {xv.x, xv.y, xv.z, xv.w};
#pragma unroll
            for (int i = 0; i < 4; i++) {
                int n = nc * 4 + i;
                u16 hv = f2bf(xf[i]);
                u16 lv = f2bf(xf[i] - bf2f(hv));
                int u = n * 256 + (c ^ ((n & 31) << 3));
                Xh[u] = hv; Xl[u] = lv;
            }
        }
    }
    __syncthreads();

    int w = tid >> 6, l = tid & 63;
    int l5 = l >> 5, l31 = l & 31;

    if (w < 4) {
        int proj = w & 1, nh = w >> 1;
        const u16* Whi = proj ? wkhi : wqhi;
        const u16* Wlo = proj ? wklo : wqlo;
        const float* bias = proj ? bk : bq;
        u16* dpk = proj ? kpk : qpk;
        float scale = proj ? 1.0f : LOG2E;
        int nl = nh * 32 + l31;
        int swz = (nl & 31) << 3;

        f32x16 acc = ZERO16;
        for (int ks = 0; ks < 16; ks++) {
            int c0 = ks * 16 + 8 * l5;
            s16x8 whi = *(const s16x8*)(Whi + l31 * 256 + c0);
            s16x8 wlo = *(const s16x8*)(Wlo + l31 * 256 + c0);
            int u = nl * 256 + (c0 ^ swz);
            s16x8 xh = *(const s16x8*)(Xh + u);
            s16x8 xl = *(const s16x8*)(Xl + u);
            acc = __builtin_amdgcn_mfma_f32_32x32x16_bf16(whi, xh, acc, 0, 0, 0);
            acc = __builtin_amdgcn_mfma_f32_32x32x16_bf16(whi, xl, acc, 0, 0, 0);
            acc = __builtin_amdgcn_mfma_f32_32x32x16_bf16(wlo, xh, acc, 0, 0, 0);
        }
        int n = n0 + nl;
        float g = gate[b * NN + n] * scale;
        size_t rowo = ((size_t)b * NN + n) * 64;
#pragma unroll
        for (int t = 0; t < 4; t++) {
            int ob = 8 * t + 4 * l5;
            unsigned h01 = 0, h23 = 0, l01 = 0, l23 = 0;
#pragma unroll
            for (int j = 0; j < 4; j++) {
                float v = (acc[4 * t + j] + bias[ob + j]) * g;
                u16 h = f2bf(v);
                u16 lo = f2bf(v - bf2f(h));
                if (j < 2) { h01 |= ((unsigned)h) << (16 * j); l01 |= ((unsigned)lo) << (16 * j); }
                else       { h23 |= ((unsigned)h) << (16 * (j - 2)); l23 |= ((unsigned)lo) << (16 * (j - 2)); }
            }
            *(unsigned*)(dpk + rowo + ob)          = h01;
            *(unsigned*)(dpk + rowo + ob + 2)      = h23;
            *(unsigned*)(dpk + rowo + 32 + ob)     = l01;
            *(unsigned*)(dpk + rowo + 32 + ob + 2) = l23;
        }
    } else {
        int vw = w - 4;
        int cB = vw * 64;
        int swz = (l31 & 31) << 3;
        f32x16 acc[2][2] = {{ZERO16, ZERO16}, {ZERO16, ZERO16}};
        for (int ks = 0; ks < 16; ks++) {
            int c0 = ks * 16 + 8 * l5;
            int u0 = l31 * 256 + (c0 ^ swz);
            s16x8 xh0 = *(const s16x8*)(Xh + u0);
            s16x8 xh1 = *(const s16x8*)(Xh + u0 + 32 * 256);
#pragma unroll
            for (int ct = 0; ct < 2; ct++) {
                s16x8 wv = *(const s16x8*)(wvbf + (size_t)(cB + ct * 32 + l31) * 256 + c0);
                acc[ct][0] = __builtin_amdgcn_mfma_f32_32x32x16_bf16(wv, xh0, acc[ct][0], 0, 0, 0);
                acc[ct][1] = __builtin_amdgcn_mfma_f32_32x32x16_bf16(wv, xh1, acc[ct][1], 0, 0, 0);
            }
        }
#pragma unroll
        for (int nh2 = 0; nh2 < 2; nh2++) {
            int n = n0 + nh2 * 32 + l31;
            int np = nswap23(n);               // store V at logical index
            float g = gate[b * NN + n];
#pragma unroll
            for (int ct = 0; ct < 2; ct++) {
#pragma unroll
                for (int r = 0; r < 16; r++) {
                    int c = cB + ct * 32 + (r & 3) + 8 * (r >> 2) + 4 * l5;
                    vbf[((size_t)b * CC + c) * NN + np] = f2bf((acc[ct][nh2][r] + bv[c]) * g);
                }
            }
        }
    }
}

// ---------------------------------------------------------------- stats ---
// 256 blocks x 8 waves (strip=w&1, ns=w>>1). Swapped energy (lane=m), lse in
// log2 domain, per-lane scalar stats. K packed direct from global.
__global__ __launch_bounds__(512, 4) void stats_kernel(
    const u16* __restrict__ qpk, const u16* __restrict__ kpk,
    float* __restrict__ lse)
{
    __shared__ float Sm[8][32], Ss[8][32];
    int bid = blockIdx.x;
    int b  = (bid >> 1) & 3;
    int mt = (bid >> 3) | ((bid & 1) << 5);
    int tid = threadIdx.x;
    int w = tid >> 6, l = tid & 63;
    int l5 = l >> 5, l31 = l & 31;
    int strip = w & 1, ns = w >> 1;
    int mS = mt * 64 + strip * 32;

    size_t qo = ((size_t)b * NN + mS + l31) * 64 + 8 * l5;
    s16x8 qh0 = *(const s16x8*)(qpk + qo),      ql0 = *(const s16x8*)(qpk + qo + 32);
    s16x8 qh1 = *(const s16x8*)(qpk + qo + 16), ql1 = *(const s16x8*)(qpk + qo + 48);

    float rmax = -1e30f, rsum = 0.f;

    for (int it = 0; it < 32; it++) {
        size_t ko = ((size_t)b * NN + it * 128 + ns * 32 + l31) * 64 + 8 * l5;
        s16x8 kh0 = *(const s16x8*)(kpk + ko),      kl0 = *(const s16x8*)(kpk + ko + 32);
        s16x8 kh1 = *(const s16x8*)(kpk + ko + 16), kl1 = *(const s16x8*)(kpk + ko + 48);
        f32x16 a = ZERO16;
        a = __builtin_amdgcn_mfma_f32_32x32x16_bf16(kh0, ql0, a, 0, 0, 0);
        a = __builtin_amdgcn_mfma_f32_32x32x16_bf16(kl0, qh0, a, 0, 0, 0);
        a = __builtin_amdgcn_mfma_f32_32x32x16_bf16(kh0, qh0, a, 0, 0, 0);
        a = __builtin_amdgcn_mfma_f32_32x32x16_bf16(kh1, ql1, a, 0, 0, 0);
        a = __builtin_amdgcn_mfma_f32_32x32x16_bf16(kl1, qh1, a, 0, 0, 0);
        a = __builtin_amdgcn_mfma_f32_32x32x16_bf16(kh1, qh1, a, 0, 0, 0);
        float t0 = fmaxf(fmaxf(a[0], a[1]),   fmaxf(a[2], a[3]));
        float t1 = fmaxf(fmaxf(a[4], a[5]),   fmaxf(a[6], a[7]));
        float t2 = fmaxf(fmaxf(a[8], a[9]),   fmaxf(a[10], a[11]));
        float t3 = fmaxf(fmaxf(a[12], a[13]), fmaxf(a[14], a[15]));
        float tm = fmaxf(fmaxf(t0, t1), fmaxf(t2, t3));
        float nm = fmaxf(rmax, tm);
        float add = 0.f;
#pragma unroll
        for (int r = 0; r < 16; r++) add += exp2f(a[r] - nm);
        rsum = rsum * exp2f(rmax - nm) + add;
        rmax = nm;
    }

    {
        float om = __shfl_xor(rmax, 32);
        float os = __shfl_xor(rsum, 32);
        float nm = fmaxf(rmax, om);
        rsum = rsum * exp2f(rmax - nm) + os * exp2f(om - nm);
        rmax = nm;
    }
    if (l < 32) { Sm[w][l] = rmax; Ss[w][l] = rsum; }
    __syncthreads();
    if (tid < 64) {
        int ww = tid >> 5;
        int mm = tid & 31;
        float M = -1e30f;
#pragma unroll
        for (int j = 0; j < 4; j++) M = fmaxf(M, Sm[ww + 2 * j][mm]);
        float S = 0.f;
#pragma unroll
        for (int j = 0; j < 4; j++)
            S += Ss[ww + 2 * j][mm] * exp2f(Sm[ww + 2 * j][mm] - M);
        lse[b * NN + mt * 64 + ww * 32 + mm] = M + log2f(S);
    }
}

// ---------------------------------------------------------------- out -----
// 512 blocks: sub=bid&7 -> b=sub>>1, ch=sub&1 (c-half); mt=bid>>3.
// 8 waves = (strip=w&1, ns=w>>1): each wave ENERGYs its own 32-n window
// (swapped, lane=m), converts P to A-frags IN REGISTERS (cvt_pk of
// consecutive regs; V stored n-bit-2/3-swapped makes this exact), and PVs
// against all 128 c into acc[4] partials. V double-buffered via
// global_load_lds; ONE barrier/iter. ns-partials reduced through LDS at end.
__global__ __launch_bounds__(512, 2) void out_kernel(
    const u16* __restrict__ qpk, const u16* __restrict__ kpk,
    const u16* __restrict__ vbf, const float* __restrict__ lse,
    const float* __restrict__ x, const float* __restrict__ gamma,
    float* __restrict__ out)
{
    __shared__ u16 Vl[2][128 * 128];   // 2 x 32 KB [c][n_logical] swizzled
    int bid = blockIdx.x;
    int sub = bid & 7;
    int b  = sub >> 1;
    int ch = sub & 1;
    int mt = bid >> 3;
    int tid = threadIdx.x;
    int w = tid >> 6, l = tid & 63;
    int l5 = l >> 5, l31 = l & 31;
    int strip = w & 1, ns = w >> 1;
    int mS = mt * 64 + strip * 32;

    size_t qo = ((size_t)b * NN + mS + l31) * 64 + 8 * l5;
    s16x8 qh0 = *(const s16x8*)(qpk + qo),      ql0 = *(const s16x8*)(qpk + qo + 32);
    s16x8 qh1 = *(const s16x8*)(qpk + qo + 16), ql1 = *(const s16x8*)(qpk + qo + 48);

    float lse_m = lse[b * NN + mS + l31];

    f32x16 acc[4] = {ZERO16, ZERO16, ZERO16, ZERO16};
    const u16* vb = vbf + ((size_t)b * CC + ch * 128) * NN;

    // stage V tile (32 KB) for iter `it` into buffer `buf`
#define STAGE(buf, it)                                                        \
    {                                                                         \
        int n0s = (it) * 128;                                                 \
        _Pragma("unroll")                                                     \
        for (int j = 0; j < 4; j++) {                                         \
            int s = j * 512 + w * 64 + l;                                     \
            int c = s >> 4, chk = s & 15;                                     \
            const u16* src = vb + (size_t)c * NN + n0s +                      \
                             ((chk * 8) ^ ((c & 15) << 3));                   \
            GLOAD_LDS16(src, &Vl[buf][(j * 512 + w * 64) * 8]);               \
        }                                                                     \
    }

    STAGE(0, 0);
    __syncthreads();

    for (int it = 0; it < 32; it++) {
        if (it < 31) STAGE((it + 1) & 1, it + 1);

        // ---- ENERGY: this wave's 32-n window, K packed direct
        int n0 = it * 128;
        size_t ko = ((size_t)b * NN + n0 + ns * 32 + l31) * 64 + 8 * l5;
        s16x8 kh0 = *(const s16x8*)(kpk + ko),      kl0 = *(const s16x8*)(kpk + ko + 32);
        s16x8 kh1 = *(const s16x8*)(kpk + ko + 16), kl1 = *(const s16x8*)(kpk + ko + 48);
        f32x16 a = ZERO16;
        a = __builtin_amdgcn_mfma_f32_32x32x16_bf16(kh0, ql0, a, 0, 0, 0);
        a = __builtin_amdgcn_mfma_f32_32x32x16_bf16(kl0, qh0, a, 0, 0, 0);
        a = __builtin_amdgcn_mfma_f32_32x32x16_bf16(kh0, qh0, a, 0, 0, 0);
        a = __builtin_amdgcn_mfma_f32_32x32x16_bf16(kh1, ql1, a, 0, 0, 0);
        a = __builtin_amdgcn_mfma_f32_32x32x16_bf16(kl1, qh1, a, 0, 0, 0);
        a = __builtin_amdgcn_mfma_f32_32x32x16_bf16(kh1, qh1, a, 0, 0, 0);

        // ---- P in registers: exp2 + cvt_pk of CONSECUTIVE regs
        float p[16];
#pragma unroll
        for (int r = 0; r < 16; r++) p[r] = exp2f(a[r] - lse_m);
        union { u32 w4[4]; s16x8 v; } pa0, pa1;
        pa0.w4[0] = cvtpk_bf16(p[0],  p[1]);
        pa0.w4[1] = cvtpk_bf16(p[2],  p[3]);
        pa0.w4[2] = cvtpk_bf16(p[4],  p[5]);
        pa0.w4[3] = cvtpk_bf16(p[6],  p[7]);
        pa1.w4[0] = cvtpk_bf16(p[8],  p[9]);
        pa1.w4[1] = cvtpk_bf16(p[10], p[11]);
        pa1.w4[2] = cvtpk_bf16(p[12], p[13]);
        pa1.w4[3] = cvtpk_bf16(p[14], p[15]);

        // ---- PV: window (32 n) x 128 c from LDS V (conflict-free swizzle)
        const u16* Vb = Vl[it & 1];
#pragma unroll
        for (int cs = 0; cs < 4; cs++) {
            int c = cs * 32 + l31;
            int rb = c * 128;
            int sw = (c & 15) << 3;
            s16x8 vv0 = *(const s16x8*)(Vb + rb + ((ns * 32 + 8 * l5) ^ sw));
            s16x8 vv1 = *(const s16x8*)(Vb + rb + ((ns * 32 + 16 + 8 * l5) ^ sw));
            acc[cs] = __builtin_amdgcn_mfma_f32_32x32x16_bf16(pa0.v, vv0, acc[cs], 0, 0, 0);
            acc[cs] = __builtin_amdgcn_mfma_f32_32x32x16_bf16(pa1.v, vv1, acc[cs], 0, 0, 0);
        }
        __syncthreads();
    }

    // ---- reduce ns-partials via LDS, add residual, write out
    float gm = gamma[0];
    float* red = (float*)&Vl[0][0];            // 32 KB scratch per cs pass
#pragma unroll
    for (int cs = 0; cs < 4; cs++) {
        __syncthreads();
#pragma unroll
        for (int t = 0; t < 4; t++) {
            float4 v4;
            v4.x = acc[cs][4 * t + 0];
            v4.y = acc[cs][4 * t + 1];
            v4.z = acc[cs][4 * t + 2];
            v4.w = acc[cs][4 * t + 3];
            *(float4*)(red + (size_t)(w * 64 + l) * 16 + 4 * t) = v4;
        }
        __syncthreads();
        if (ns == 0) {
            int c = ch * 128 + cs * 32 + l31;
#pragma unroll
            for (int t = 0; t < 4; t++) {
                float4 s0 = *(const float4*)(red + (size_t)((strip + 0) * 64 + l) * 16 + 4 * t);
                float4 s1 = *(const float4*)(red + (size_t)((strip + 2) * 64 + l) * 16 + 4 * t);
                float4 s2 = *(const float4*)(red + (size_t)((strip + 4) * 64 + l) * 16 + 4 * t);
                float4 s3 = *(const float4*)(red + (size_t)((strip + 6) * 64 + l) * 16 + 4 * t);
                size_t o = ((size_t)b * CC + c) * NN + mS + 8 * t + 4 * l5;
                float4 x4 = *(const float4*)(x + o);
                float4 r4;
                r4.x = fmaf(gm, s0.x + s1.x + s2.x + s3.x, x4.x);
                r4.y = fmaf(gm, s0.y + s1.y + s2.y + s3.y, x4.y);
                r4.z = fmaf(gm, s0.z + s1.z + s2.z + s3.z, x4.z);
                r4.w = fmaf(gm, s0.w + s1.w + s2.w + s3.w, x4.w);
                *(float4*)(out + o) = r4;
            }
        }
    }
#undef STAGE
}

// ---------------------------------------------------------------- launch --
extern "C" void kernel_launch(void* const* d_in, const int* in_sizes, int n_in,
                              void* d_out, int out_size, void* d_ws, size_t ws_size,
                              hipStream_t stream)
{
    const float* x     = (const float*)d_in[0];
    const float* g0    = (const float*)d_in[1];
    const float* Wq    = (const float*)d_in[2];
    const float* bq    = (const float*)d_in[3];
    const float* Wk    = (const float*)d_in[4];
    const float* bk    = (const float*)d_in[5];
    const float* Wv    = (const float*)d_in[6];
    const float* bv    = (const float*)d_in[7];
    const float* gamma = (const float*)d_in[8];
    float* out = (float*)d_out;

    char* p = (char*)d_ws;
    u16* qpk = (u16*)p; p += (size_t)4 * NN * 64 * 2;   // 2 MB packed [n][hi|lo]
    u16* kpk = (u16*)p; p += (size_t)4 * NN * 64 * 2;   // 2 MB
    u16* vbf = (u16*)p; p += (size_t)4 * CC * NN * 2;   // 8 MB, n-interleaved
    float* gate = (float*)p; p += (size_t)4 * NN * 4;
    float* lse  = (float*)p; p += (size_t)4 * NN * 4;
    u16* wqhi = (u16*)p; p += 8192 * 2;
    u16* wqlo = (u16*)p; p += 8192 * 2;
    u16* wkhi = (u16*)p; p += 8192 * 2;
    u16* wklo = (u16*)p; p += 8192 * 2;
    u16* wvbf = (u16*)p; p += 65536 * 2;

    hipLaunchKernelGGL(gate_kernel, dim3(64), dim3(256), 0, stream,
                       g0, Wq, Wk, Wv, gate, wqhi, wqlo, wkhi, wklo, wvbf);
    hipLaunchKernelGGL(qkv_kernel, dim3(256), dim3(512), 0, stream,
                       x, wqhi, wqlo, wkhi, wklo, wvbf, bq, bk, bv, gate,
                       qpk, kpk, vbf);
    hipLaunchKernelGGL(stats_kernel, dim3(256), dim3(512), 0, stream,
                       qpk, kpk, lse);
    hipLaunchKernelGGL(out_kernel, dim3(512), dim3(512), 0, stream,
                       qpk, kpk, vbf, lse, x, gamma, out);
}

// Round 11
// 157.508 us; speedup vs baseline: 1.4916x; 1.2228x over previous
//
#include <hip/hip_runtime.h>
#include <math.h>

#define NN 4096
#define CC 256

typedef unsigned short u16;
typedef unsigned int u32;
typedef float f32x16 __attribute__((ext_vector_type(16)));
typedef short s16x8 __attribute__((ext_vector_type(8)));

#define ZERO16 {0.f,0.f,0.f,0.f,0.f,0.f,0.f,0.f,0.f,0.f,0.f,0.f,0.f,0.f,0.f,0.f}
#define LOG2E 1.4426950408889634f

#define GLOAD_LDS16(gsrc, ldst) \
    __builtin_amdgcn_global_load_lds((const __attribute__((address_space(1))) unsigned int*)(gsrc), \
                                     (__attribute__((address_space(3))) unsigned int*)(ldst), 16, 0, 0)

__device__ __forceinline__ u16 f2bf(float f){
    unsigned u = __float_as_uint(f);
    return (u16)((u + 0x7fffu + ((u >> 16) & 1u)) >> 16);
}
__device__ __forceinline__ float bf2f(u16 h){
    return __uint_as_float(((unsigned)h) << 16);
}
__device__ __forceinline__ u32 cvtpk_bf16(float a, float b){
    u32 r;
    asm("v_cvt_pk_bf16_f32 %0, %1, %2" : "=v"(r) : "v"(a), "v"(b));
    return r;
}
// n-index involution: swap bits 2 and 3 (V stored so PV A-frags are lane-local
// cvt_pk of consecutive energy-accumulator registers)
__device__ __forceinline__ int nswap23(int n){
    return (n & ~12) | ((n & 4) << 1) | ((n & 8) >> 1);
}

// ---------------------------------------------------------------- gate + W prep
__global__ __launch_bounds__(256) void gate_kernel(
    const float* __restrict__ g0, const float* __restrict__ Wq,
    const float* __restrict__ Wk, const float* __restrict__ Wv,
    float* __restrict__ gate,
    u16* __restrict__ wqhi, u16* __restrict__ wqlo,
    u16* __restrict__ wkhi, u16* __restrict__ wklo,
    u16* __restrict__ wvbf)
{
    int idx = blockIdx.x * 256 + threadIdx.x;      // 0..16383
    int b  = idx >> 12;
    int hw = idx & 4095;
    int h = hw >> 6, w = hw & 63;
    float ys = h * (31.0f / 63.0f);
    float xs = w * (31.0f / 63.0f);
    int y0 = (int)ys, x0 = (int)xs;
    int y1 = min(y0 + 1, 31), x1 = min(x0 + 1, 31);
    float wy = ys - (float)y0, wx = xs - (float)x0;
    const float* g = g0 + b * 1024;
    float g00 = g[y0 * 32 + x0], g01 = g[y0 * 32 + x1];
    float g10 = g[y1 * 32 + x0], g11 = g[y1 * 32 + x1];
    float top = g00 * (1.0f - wx) + g01 * wx;
    float bot = g10 * (1.0f - wx) + g11 * wx;
    float val = top * (1.0f - wy) + bot * wy;
    gate[idx] = 1.0f + 1.0f / (1.0f + __expf(-val));

    if (idx < 8192) {
        float a = Wq[idx];
        u16 ha = f2bf(a);
        wqhi[idx] = ha; wqlo[idx] = f2bf(a - bf2f(ha));
        float c = Wk[idx];
        u16 hc = f2bf(c);
        wkhi[idx] = hc; wklo[idx] = f2bf(c - bf2f(hc));
    }
#pragma unroll
    for (int j = 0; j < 4; j++)
        wvbf[idx + j * 16384] = f2bf(Wv[idx + j * 16384]);
}

// ---------------------------------------------------------------- qkv -----
// 256 blocks (b, nt of 64 n). x staged once in LDS as bf16 hi/lo [n][c] swizzled.
// 8 waves: 0..3 = q/k (hi/lo split, PACKED rows [n][hi|lo], q pre-scaled by
// log2e); 4..7 = v -> bf16 [b][c][n'] with n' = nswap23(n).
__global__ __launch_bounds__(512, 4) void qkv_kernel(
    const float* __restrict__ x,
    const u16* __restrict__ wqhi, const u16* __restrict__ wqlo,
    const u16* __restrict__ wkhi, const u16* __restrict__ wklo,
    const u16* __restrict__ wvbf,
    const float* __restrict__ bq, const float* __restrict__ bk,
    const float* __restrict__ bv, const float* __restrict__ gate,
    u16* __restrict__ qpk, u16* __restrict__ kpk,
    u16* __restrict__ vbf)
{
    __shared__ u16 Xh[64 * 256];   // [n][c] swizzled, 32 KB
    __shared__ u16 Xl[64 * 256];   // 32 KB
    int bid = blockIdx.x;
    int b  = (bid >> 1) & 3;
    int nt = (bid >> 3) | ((bid & 1) << 5);
    int n0 = nt * 64;
    int tid = threadIdx.x;

    {
        const float* xb = x + (size_t)b * CC * NN;
        int cb = tid >> 4;
        int nc = tid & 15;
#pragma unroll
        for (int j = 0; j < 8; j++) {
            int c = cb + 32 * j;
            float4 xv = *(const float4*)(xb + (size_t)c * NN + n0 + nc * 4);
            float xf[4] = {xv.x, xv.y, xv.z, xv.w};
#pragma unroll
            for (int i = 0; i < 4; i++) {
                int n = nc * 4 + i;
                u16 hv = f2bf(xf[i]);
                u16 lv = f2bf(xf[i] - bf2f(hv));
                int u = n * 256 + (c ^ ((n & 31) << 3));
                Xh[u] = hv; Xl[u] = lv;
            }
        }
    }
    __syncthreads();

    int w = tid >> 6, l = tid & 63;
    int l5 = l >> 5, l31 = l & 31;

    if (w < 4) {
        int proj = w & 1, nh = w >> 1;
        const u16* Whi = proj ? wkhi : wqhi;
        const u16* Wlo = proj ? wklo : wqlo;
        const float* bias = proj ? bk : bq;
        u16* dpk = proj ? kpk : qpk;
        float scale = proj ? 1.0f : LOG2E;
        int nl = nh * 32 + l31;
        int swz = (nl & 31) << 3;

        f32x16 acc = ZERO16;
        for (int ks = 0; ks < 16; ks++) {
            int c0 = ks * 16 + 8 * l5;
            s16x8 whi = *(const s16x8*)(Whi + l31 * 256 + c0);
            s16x8 wlo = *(const s16x8*)(Wlo + l31 * 256 + c0);
            int u = nl * 256 + (c0 ^ swz);
            s16x8 xh = *(const s16x8*)(Xh + u);
            s16x8 xl = *(const s16x8*)(Xl + u);
            acc = __builtin_amdgcn_mfma_f32_32x32x16_bf16(whi, xh, acc, 0, 0, 0);
            acc = __builtin_amdgcn_mfma_f32_32x32x16_bf16(whi, xl, acc, 0, 0, 0);
            acc = __builtin_amdgcn_mfma_f32_32x32x16_bf16(wlo, xh, acc, 0, 0, 0);
        }
        int n = n0 + nl;
        float g = gate[b * NN + n] * scale;
        size_t rowo = ((size_t)b * NN + n) * 64;
#pragma unroll
        for (int t = 0; t < 4; t++) {
            int ob = 8 * t + 4 * l5;
            unsigned h01 = 0, h23 = 0, l01 = 0, l23 = 0;
#pragma unroll
            for (int j = 0; j < 4; j++) {
                float v = (acc[4 * t + j] + bias[ob + j]) * g;
                u16 h = f2bf(v);
                u16 lo = f2bf(v - bf2f(h));
                if (j < 2) { h01 |= ((unsigned)h) << (16 * j); l01 |= ((unsigned)lo) << (16 * j); }
                else       { h23 |= ((unsigned)h) << (16 * (j - 2)); l23 |= ((unsigned)lo) << (16 * (j - 2)); }
            }
            *(unsigned*)(dpk + rowo + ob)          = h01;
            *(unsigned*)(dpk + rowo + ob + 2)      = h23;
            *(unsigned*)(dpk + rowo + 32 + ob)     = l01;
            *(unsigned*)(dpk + rowo + 32 + ob + 2) = l23;
        }
    } else {
        int vw = w - 4;
        int cB = vw * 64;
        int swz = (l31 & 31) << 3;
        f32x16 acc[2][2] = {{ZERO16, ZERO16}, {ZERO16, ZERO16}};
        for (int ks = 0; ks < 16; ks++) {
            int c0 = ks * 16 + 8 * l5;
            int u0 = l31 * 256 + (c0 ^ swz);
            s16x8 xh0 = *(const s16x8*)(Xh + u0);
            s16x8 xh1 = *(const s16x8*)(Xh + u0 + 32 * 256);
#pragma unroll
            for (int ct = 0; ct < 2; ct++) {
                s16x8 wv = *(const s16x8*)(wvbf + (size_t)(cB + ct * 32 + l31) * 256 + c0);
                acc[ct][0] = __builtin_amdgcn_mfma_f32_32x32x16_bf16(wv, xh0, acc[ct][0], 0, 0, 0);
                acc[ct][1] = __builtin_amdgcn_mfma_f32_32x32x16_bf16(wv, xh1, acc[ct][1], 0, 0, 0);
            }
        }
#pragma unroll
        for (int nh2 = 0; nh2 < 2; nh2++) {
            int n = n0 + nh2 * 32 + l31;
            int np = nswap23(n);
            float g = gate[b * NN + n];
#pragma unroll
            for (int ct = 0; ct < 2; ct++) {
#pragma unroll
                for (int r = 0; r < 16; r++) {
                    int c = cB + ct * 32 + (r & 3) + 8 * (r >> 2) + 4 * l5;
                    vbf[((size_t)b * CC + c) * NN + np] = f2bf((acc[ct][nh2][r] + bv[c]) * g);
                }
            }
        }
    }
}

// ---------------------------------------------------------------- stats ---
// 256 blocks x 8 waves (strip=w&1, ns=w>>1). Swapped energy (lane=m), lse in
// log2 domain, per-lane scalar stats. K packed direct from global.
__global__ __launch_bounds__(512, 4) void stats_kernel(
    const u16* __restrict__ qpk, const u16* __restrict__ kpk,
    float* __restrict__ lse)
{
    __shared__ float Sm[8][32], Ss[8][32];
    int bid = blockIdx.x;
    int b  = (bid >> 1) & 3;
    int mt = (bid >> 3) | ((bid & 1) << 5);
    int tid = threadIdx.x;
    int w = tid >> 6, l = tid & 63;
    int l5 = l >> 5, l31 = l & 31;
    int strip = w & 1, ns = w >> 1;
    int mS = mt * 64 + strip * 32;

    size_t qo = ((size_t)b * NN + mS + l31) * 64 + 8 * l5;
    s16x8 qh0 = *(const s16x8*)(qpk + qo),      ql0 = *(const s16x8*)(qpk + qo + 32);
    s16x8 qh1 = *(const s16x8*)(qpk + qo + 16), ql1 = *(const s16x8*)(qpk + qo + 48);

    float rmax = -1e30f, rsum = 0.f;

    for (int it = 0; it < 32; it++) {
        size_t ko = ((size_t)b * NN + it * 128 + ns * 32 + l31) * 64 + 8 * l5;
        s16x8 kh0 = *(const s16x8*)(kpk + ko),      kl0 = *(const s16x8*)(kpk + ko + 32);
        s16x8 kh1 = *(const s16x8*)(kpk + ko + 16), kl1 = *(const s16x8*)(kpk + ko + 48);
        f32x16 a = ZERO16;
        a = __builtin_amdgcn_mfma_f32_32x32x16_bf16(kh0, ql0, a, 0, 0, 0);
        a = __builtin_amdgcn_mfma_f32_32x32x16_bf16(kl0, qh0, a, 0, 0, 0);
        a = __builtin_amdgcn_mfma_f32_32x32x16_bf16(kh0, qh0, a, 0, 0, 0);
        a = __builtin_amdgcn_mfma_f32_32x32x16_bf16(kh1, ql1, a, 0, 0, 0);
        a = __builtin_amdgcn_mfma_f32_32x32x16_bf16(kl1, qh1, a, 0, 0, 0);
        a = __builtin_amdgcn_mfma_f32_32x32x16_bf16(kh1, qh1, a, 0, 0, 0);
        float t0 = fmaxf(fmaxf(a[0], a[1]),   fmaxf(a[2], a[3]));
        float t1 = fmaxf(fmaxf(a[4], a[5]),   fmaxf(a[6], a[7]));
        float t2 = fmaxf(fmaxf(a[8], a[9]),   fmaxf(a[10], a[11]));
        float t3 = fmaxf(fmaxf(a[12], a[13]), fmaxf(a[14], a[15]));
        float tm = fmaxf(fmaxf(t0, t1), fmaxf(t2, t3));
        float nm = fmaxf(rmax, tm);
        float add = 0.f;
#pragma unroll
        for (int r = 0; r < 16; r++) add += exp2f(a[r] - nm);
        rsum = rsum * exp2f(rmax - nm) + add;
        rmax = nm;
    }

    {
        float om = __shfl_xor(rmax, 32);
        float os = __shfl_xor(rsum, 32);
        float nm = fmaxf(rmax, om);
        rsum = rsum * exp2f(rmax - nm) + os * exp2f(om - nm);
        rmax = nm;
    }
    if (l < 32) { Sm[w][l] = rmax; Ss[w][l] = rsum; }
    __syncthreads();
    if (tid < 64) {
        int ww = tid >> 5;
        int mm = tid & 31;
        float M = -1e30f;
#pragma unroll
        for (int j = 0; j < 4; j++) M = fmaxf(M, Sm[ww + 2 * j][mm]);
        float S = 0.f;
#pragma unroll
        for (int j = 0; j < 4; j++)
            S += Ss[ww + 2 * j][mm] * exp2f(Sm[ww + 2 * j][mm] - M);
        lse[b * NN + mt * 64 + ww * 32 + mm] = M + log2f(S);
    }
}

// ---------------------------------------------------------------- out -----
// 256 blocks: sub=bid&7 -> b=sub&3, mt-parity=sub>>2 (XCD pins (b,parity):
// V 2MB + K 0.5MB L2-resident). Block = 64 m x 256 c, n-tile 128, LDS 128 KB
// (V dbuf), 1 block/CU. 8 waves = (strip=w&1, ns=w>>1): energy ONCE per
// block per n-window (no duplication), P in registers (exp2+cvt_pk),
// PV vs all 256 c -> acc[8]. ns-partials reduced once at end (pitch-33 LDS).
__global__ __launch_bounds__(512, 2) void out_kernel(
    const u16* __restrict__ qpk, const u16* __restrict__ kpk,
    const u16* __restrict__ vbf, const float* __restrict__ lse,
    const float* __restrict__ x, const float* __restrict__ gamma,
    float* __restrict__ out)
{
    __shared__ u16 Vl[2][256 * 128];   // 2 x 64 KB [c][n_logical] swizzled
    int bid = blockIdx.x;
    int sub = bid & 7;
    int b  = sub & 3;
    int mt = (bid >> 3) + 32 * (sub >> 2);
    int tid = threadIdx.x;
    int w = tid >> 6, l = tid & 63;
    int l5 = l >> 5, l31 = l & 31;
    int strip = w & 1, ns = w >> 1;
    int mS = mt * 64 + strip * 32;

    size_t qo = ((size_t)b * NN + mS + l31) * 64 + 8 * l5;
    s16x8 qh0 = *(const s16x8*)(qpk + qo),      ql0 = *(const s16x8*)(qpk + qo + 32);
    s16x8 qh1 = *(const s16x8*)(qpk + qo + 16), ql1 = *(const s16x8*)(qpk + qo + 48);

    float lse_m = lse[b * NN + mS + l31];

    f32x16 acc[8] = {ZERO16, ZERO16, ZERO16, ZERO16,
                     ZERO16, ZERO16, ZERO16, ZERO16};
    const u16* vb = vbf + (size_t)b * CC * NN;

    // stage full V tile (256c x 128n = 64 KB): 8 x gload_lds16 per thread
#define STAGE(buf, it)                                                        \
    {                                                                         \
        int n0s = (it) * 128;                                                 \
        _Pragma("unroll")                                                     \
        for (int j = 0; j < 8; j++) {                                         \
            int s = j * 512 + w * 64 + l;                                     \
            int c = s >> 4, chk = s & 15;                                     \
            const u16* src = vb + (size_t)c * NN + n0s +                      \
                             ((chk * 8) ^ ((c & 15) << 3));                   \
            GLOAD_LDS16(src, &Vl[buf][(j * 512 + w * 64) * 8]);               \
        }                                                                     \
    }

    STAGE(0, 0);
    __syncthreads();

    for (int it = 0; it < 32; it++) {
        if (it < 31) STAGE((it + 1) & 1, it + 1);

        // ---- ENERGY: this wave's 32-n window (once per block), K packed
        int n0 = it * 128;
        size_t ko = ((size_t)b * NN + n0 + ns * 32 + l31) * 64 + 8 * l5;
        s16x8 kh0 = *(const s16x8*)(kpk + ko),      kl0 = *(const s16x8*)(kpk + ko + 32);
        s16x8 kh1 = *(const s16x8*)(kpk + ko + 16), kl1 = *(const s16x8*)(kpk + ko + 48);
        f32x16 a = ZERO16;
        a = __builtin_amdgcn_mfma_f32_32x32x16_bf16(kh0, ql0, a, 0, 0, 0);
        a = __builtin_amdgcn_mfma_f32_32x32x16_bf16(kl0, qh0, a, 0, 0, 0);
        a = __builtin_amdgcn_mfma_f32_32x32x16_bf16(kh0, qh0, a, 0, 0, 0);
        a = __builtin_amdgcn_mfma_f32_32x32x16_bf16(kh1, ql1, a, 0, 0, 0);
        a = __builtin_amdgcn_mfma_f32_32x32x16_bf16(kl1, qh1, a, 0, 0, 0);
        a = __builtin_amdgcn_mfma_f32_32x32x16_bf16(kh1, qh1, a, 0, 0, 0);

        // ---- P in registers: exp2 + cvt_pk of CONSECUTIVE regs
        union { u32 w4[4]; s16x8 v; } pa0, pa1;
        pa0.w4[0] = cvtpk_bf16(exp2f(a[0]  - lse_m), exp2f(a[1]  - lse_m));
        pa0.w4[1] = cvtpk_bf16(exp2f(a[2]  - lse_m), exp2f(a[3]  - lse_m));
        pa0.w4[2] = cvtpk_bf16(exp2f(a[4]  - lse_m), exp2f(a[5]  - lse_m));
        pa0.w4[3] = cvtpk_bf16(exp2f(a[6]  - lse_m), exp2f(a[7]  - lse_m));
        pa1.w4[0] = cvtpk_bf16(exp2f(a[8]  - lse_m), exp2f(a[9]  - lse_m));
        pa1.w4[1] = cvtpk_bf16(exp2f(a[10] - lse_m), exp2f(a[11] - lse_m));
        pa1.w4[2] = cvtpk_bf16(exp2f(a[12] - lse_m), exp2f(a[13] - lse_m));
        pa1.w4[3] = cvtpk_bf16(exp2f(a[14] - lse_m), exp2f(a[15] - lse_m));

        // ---- PV: window (32 n) x 256 c from LDS V (conflict-free swizzle)
        const u16* Vb = Vl[it & 1];
#pragma unroll
        for (int cs = 0; cs < 8; cs++) {
            int c = cs * 32 + l31;
            int rb = c * 128;
            int sw = (c & 15) << 3;
            s16x8 vv0 = *(const s16x8*)(Vb + rb + ((ns * 32 + 8 * l5) ^ sw));
            s16x8 vv1 = *(const s16x8*)(Vb + rb + ((ns * 32 + 16 + 8 * l5) ^ sw));
            acc[cs] = __builtin_amdgcn_mfma_f32_32x32x16_bf16(pa0.v, vv0, acc[cs], 0, 0, 0);
            acc[cs] = __builtin_amdgcn_mfma_f32_32x32x16_bf16(pa1.v, vv1, acc[cs], 0, 0, 0);
        }
        __syncthreads();
    }

    // ---- epilogue: reduce ns-partials (4 per output), 4 passes of 2 cs.
    // Pitch-33 layout: bank = (33*row + col) % 32 = (row + col) % 32 -> CF.
    float gm = gamma[0];
    float* red = (float*)&Vl[0][0];
    int row = w * 64 + l;
#pragma unroll
    for (int p = 0; p < 4; p++) {
        int cs0 = 2 * p;
#pragma unroll
        for (int q = 0; q < 4; q++) {
            float4 v4;
            v4.x = acc[cs0][4 * q + 0]; v4.y = acc[cs0][4 * q + 1];
            v4.z = acc[cs0][4 * q + 2]; v4.w = acc[cs0][4 * q + 3];
            *(float4*)(red + row * 33 + 4 * q) = v4;
            float4 w4;
            w4.x = acc[cs0 + 1][4 * q + 0]; w4.y = acc[cs0 + 1][4 * q + 1];
            w4.z = acc[cs0 + 1][4 * q + 2]; w4.w = acc[cs0 + 1][4 * q + 3];
            *(float4*)(red + row * 33 + 16 + 4 * q) = w4;
        }
        __syncthreads();
        int strip_o = w & 1, csi = (w >> 1) & 1, eh = w >> 2;
        int c = (cs0 + csi) * 32 + l31;
#pragma unroll
        for (int t = 0; t < 2; t++) {
            int ebase = eh * 8 + 4 * t;
            float4 s = {0.f, 0.f, 0.f, 0.f};
#pragma unroll
            for (int j = 0; j < 4; j++) {
                float4 v = *(const float4*)(red + (size_t)((strip_o + 2 * j) * 64 + l) * 33
                                            + csi * 16 + ebase);
                s.x += v.x; s.y += v.y; s.z += v.z; s.w += v.w;
            }
            int m = mt * 64 + strip_o * 32 + 8 * (eh * 2 + t) + 4 * l5;
            size_t o = ((size_t)b * CC + c) * NN + m;
            float4 x4 = *(const float4*)(x + o);
            float4 r4;
            r4.x = fmaf(gm, s.x, x4.x);
            r4.y = fmaf(gm, s.y, x4.y);
            r4.z = fmaf(gm, s.z, x4.z);
            r4.w = fmaf(gm, s.w, x4.w);
            *(float4*)(out + o) = r4;
        }
        __syncthreads();
    }
#undef STAGE
}

// ---------------------------------------------------------------- launch --
extern "C" void kernel_launch(void* const* d_in, const int* in_sizes, int n_in,
                              void* d_out, int out_size, void* d_ws, size_t ws_size,
                              hipStream_t stream)
{
    const float* x     = (const float*)d_in[0];
    const float* g0    = (const float*)d_in[1];
    const float* Wq    = (const float*)d_in[2];
    const float* bq    = (const float*)d_in[3];
    const float* Wk    = (const float*)d_in[4];
    const float* bk    = (const float*)d_in[5];
    const float* Wv    = (const float*)d_in[6];
    const float* bv    = (const float*)d_in[7];
    const float* gamma = (const float*)d_in[8];
    float* out = (float*)d_out;

    char* p = (char*)d_ws;
    u16* qpk = (u16*)p; p += (size_t)4 * NN * 64 * 2;   // 2 MB packed [n][hi|lo]
    u16* kpk = (u16*)p; p += (size_t)4 * NN * 64 * 2;   // 2 MB
    u16* vbf = (u16*)p; p += (size_t)4 * CC * NN * 2;   // 8 MB, n-interleaved
    float* gate = (float*)p; p += (size_t)4 * NN * 4;
    float* lse  = (float*)p; p += (size_t)4 * NN * 4;
    u16* wqhi = (u16*)p; p += 8192 * 2;
    u16* wqlo = (u16*)p; p += 8192 * 2;
    u16* wkhi = (u16*)p; p += 8192 * 2;
    u16* wklo = (u16*)p; p += 8192 * 2;
    u16* wvbf = (u16*)p; p += 65536 * 2;

    hipLaunchKernelGGL(gate_kernel, dim3(64), dim3(256), 0, stream,
                       g0, Wq, Wk, Wv, gate, wqhi, wqlo, wkhi, wklo, wvbf);
    hipLaunchKernelGGL(qkv_kernel, dim3(256), dim3(512), 0, stream,
                       x, wqhi, wqlo, wkhi, wklo, wvbf, bq, bk, bv, gate,
                       qpk, kpk, vbf);
    hipLaunchKernelGGL(stats_kernel, dim3(256), dim3(512), 0, stream,
                       qpk, kpk, lse);
    hipLaunchKernelGGL(out_kernel, dim3(256), dim3(512), 0, stream,
                       qpk, kpk, vbf, lse, x, gamma, out);
}

// Round 12
// 143.207 us; speedup vs baseline: 1.6405x; 1.0999x over previous
//
#include <hip/hip_runtime.h>
#include <math.h>

#define NN 4096
#define CC 256

typedef unsigned short u16;
typedef unsigned int u32;
typedef float f32x16 __attribute__((ext_vector_type(16)));
typedef short s16x8 __attribute__((ext_vector_type(8)));

#define ZERO16 {0.f,0.f,0.f,0.f,0.f,0.f,0.f,0.f,0.f,0.f,0.f,0.f,0.f,0.f,0.f,0.f}
#define LOG2E 1.4426950408889634f

#define GLOAD_LDS16(gsrc, ldst) \
    __builtin_amdgcn_global_load_lds((const __attribute__((address_space(1))) unsigned int*)(gsrc), \
                                     (__attribute__((address_space(3))) unsigned int*)(ldst), 16, 0, 0)

__device__ __forceinline__ u16 f2bf(float f){
    unsigned u = __float_as_uint(f);
    return (u16)((u + 0x7fffu + ((u >> 16) & 1u)) >> 16);
}
__device__ __forceinline__ float bf2f(u16 h){
    return __uint_as_float(((unsigned)h) << 16);
}
__device__ __forceinline__ u32 cvtpk_bf16(float a, float b){
    u32 r;
    asm("v_cvt_pk_bf16_f32 %0, %1, %2" : "=v"(r) : "v"(a), "v"(b));
    return r;
}
// n-index involution: swap bits 2 and 3 (V stored so PV A-frags are lane-local
// cvt_pk of consecutive energy-accumulator registers)
__device__ __forceinline__ int nswap23(int n){
    return (n & ~12) | ((n & 4) << 1) | ((n & 8) >> 1);
}

// ---------------------------------------------------------------- gate + W prep
__global__ __launch_bounds__(256) void gate_kernel(
    const float* __restrict__ g0, const float* __restrict__ Wq,
    const float* __restrict__ Wk, const float* __restrict__ Wv,
    float* __restrict__ gate,
    u16* __restrict__ wqhi, u16* __restrict__ wqlo,
    u16* __restrict__ wkhi, u16* __restrict__ wklo,
    u16* __restrict__ wvbf)
{
    int idx = blockIdx.x * 256 + threadIdx.x;      // 0..16383
    int b  = idx >> 12;
    int hw = idx & 4095;
    int h = hw >> 6, w = hw & 63;
    float ys = h * (31.0f / 63.0f);
    float xs = w * (31.0f / 63.0f);
    int y0 = (int)ys, x0 = (int)xs;
    int y1 = min(y0 + 1, 31), x1 = min(x0 + 1, 31);
    float wy = ys - (float)y0, wx = xs - (float)x0;
    const float* g = g0 + b * 1024;
    float g00 = g[y0 * 32 + x0], g01 = g[y0 * 32 + x1];
    float g10 = g[y1 * 32 + x0], g11 = g[y1 * 32 + x1];
    float top = g00 * (1.0f - wx) + g01 * wx;
    float bot = g10 * (1.0f - wx) + g11 * wx;
    float val = top * (1.0f - wy) + bot * wy;
    gate[idx] = 1.0f + 1.0f / (1.0f + __expf(-val));

    if (idx < 8192) {
        float a = Wq[idx];
        u16 ha = f2bf(a);
        wqhi[idx] = ha; wqlo[idx] = f2bf(a - bf2f(ha));
        float c = Wk[idx];
        u16 hc = f2bf(c);
        wkhi[idx] = hc; wklo[idx] = f2bf(c - bf2f(hc));
    }
#pragma unroll
    for (int j = 0; j < 4; j++)
        wvbf[idx + j * 16384] = f2bf(Wv[idx + j * 16384]);
}

// ---------------------------------------------------------------- qkv -----
// 256 blocks (b, nt of 64 n). x staged once in LDS as bf16 hi/lo [n][c] swizzled.
// 8 waves: 0..3 = q/k (hi/lo split, PACKED rows [n][hi|lo], q pre-scaled by
// log2e); 4..7 = v -> bf16 [b][c][n'] with n' = nswap23(n).
__global__ __launch_bounds__(512, 4) void qkv_kernel(
    const float* __restrict__ x,
    const u16* __restrict__ wqhi, const u16* __restrict__ wqlo,
    const u16* __restrict__ wkhi, const u16* __restrict__ wklo,
    const u16* __restrict__ wvbf,
    const float* __restrict__ bq, const float* __restrict__ bk,
    const float* __restrict__ bv, const float* __restrict__ gate,
    u16* __restrict__ qpk, u16* __restrict__ kpk,
    u16* __restrict__ vbf)
{
    __shared__ u16 Xh[64 * 256];   // [n][c] swizzled, 32 KB
    __shared__ u16 Xl[64 * 256];   // 32 KB
    int bid = blockIdx.x;
    int b  = (bid >> 1) & 3;
    int nt = (bid >> 3) | ((bid & 1) << 5);
    int n0 = nt * 64;
    int tid = threadIdx.x;

    {
        const float* xb = x + (size_t)b * CC * NN;
        int cb = tid >> 4;
        int nc = tid & 15;
#pragma unroll
        for (int j = 0; j < 8; j++) {
            int c = cb + 32 * j;
            float4 xv = *(const float4*)(xb + (size_t)c * NN + n0 + nc * 4);
            float xf[4] = {xv.x, xv.y, xv.z, xv.w};
#pragma unroll
            for (int i = 0; i < 4; i++) {
                int n = nc * 4 + i;
                u16 hv = f2bf(xf[i]);
                u16 lv = f2bf(xf[i] - bf2f(hv));
                int u = n * 256 + (c ^ ((n & 31) << 3));
                Xh[u] = hv; Xl[u] = lv;
            }
        }
    }
    __syncthreads();

    int w = tid >> 6, l = tid & 63;
    int l5 = l >> 5, l31 = l & 31;

    if (w < 4) {
        int proj = w & 1, nh = w >> 1;
        const u16* Whi = proj ? wkhi : wqhi;
        const u16* Wlo = proj ? wklo : wqlo;
        const float* bias = proj ? bk : bq;
        u16* dpk = proj ? kpk : qpk;
        float scale = proj ? 1.0f : LOG2E;
        int nl = nh * 32 + l31;
        int swz = (nl & 31) << 3;

        f32x16 acc = ZERO16;
        for (int ks = 0; ks < 16; ks++) {
            int c0 = ks * 16 + 8 * l5;
            s16x8 whi = *(const s16x8*)(Whi + l31 * 256 + c0);
            s16x8 wlo = *(const s16x8*)(Wlo + l31 * 256 + c0);
            int u = nl * 256 + (c0 ^ swz);
            s16x8 xh = *(const s16x8*)(Xh + u);
            s16x8 xl = *(const s16x8*)(Xl + u);
            acc = __builtin_amdgcn_mfma_f32_32x32x16_bf16(whi, xh, acc, 0, 0, 0);
            acc = __builtin_amdgcn_mfma_f32_32x32x16_bf16(whi, xl, acc, 0, 0, 0);
            acc = __builtin_amdgcn_mfma_f32_32x32x16_bf16(wlo, xh, acc, 0, 0, 0);
        }
        int n = n0 + nl;
        float g = gate[b * NN + n] * scale;
        size_t rowo = ((size_t)b * NN + n) * 64;
#pragma unroll
        for (int t = 0; t < 4; t++) {
            int ob = 8 * t + 4 * l5;
            unsigned h01 = 0, h23 = 0, l01 = 0, l23 = 0;
#pragma unroll
            for (int j = 0; j < 4; j++) {
                float v = (acc[4 * t + j] + bias[ob + j]) * g;
                u16 h = f2bf(v);
                u16 lo = f2bf(v - bf2f(h));
                if (j < 2) { h01 |= ((unsigned)h) << (16 * j); l01 |= ((unsigned)lo) << (16 * j); }
                else       { h23 |= ((unsigned)h) << (16 * (j - 2)); l23 |= ((unsigned)lo) << (16 * (j - 2)); }
            }
            *(unsigned*)(dpk + rowo + ob)          = h01;
            *(unsigned*)(dpk + rowo + ob + 2)      = h23;
            *(unsigned*)(dpk + rowo + 32 + ob)     = l01;
            *(unsigned*)(dpk + rowo + 32 + ob + 2) = l23;
        }
    } else {
        int vw = w - 4;
        int cB = vw * 64;
        int swz = (l31 & 31) << 3;
        f32x16 acc[2][2] = {{ZERO16, ZERO16}, {ZERO16, ZERO16}};
        for (int ks = 0; ks < 16; ks++) {
            int c0 = ks * 16 + 8 * l5;
            int u0 = l31 * 256 + (c0 ^ swz);
            s16x8 xh0 = *(const s16x8*)(Xh + u0);
            s16x8 xh1 = *(const s16x8*)(Xh + u0 + 32 * 256);
#pragma unroll
            for (int ct = 0; ct < 2; ct++) {
                s16x8 wv = *(const s16x8*)(wvbf + (size_t)(cB + ct * 32 + l31) * 256 + c0);
                acc[ct][0] = __builtin_amdgcn_mfma_f32_32x32x16_bf16(wv, xh0, acc[ct][0], 0, 0, 0);
                acc[ct][1] = __builtin_amdgcn_mfma_f32_32x32x16_bf16(wv, xh1, acc[ct][1], 0, 0, 0);
            }
        }
#pragma unroll
        for (int nh2 = 0; nh2 < 2; nh2++) {
            int n = n0 + nh2 * 32 + l31;
            int np = nswap23(n);
            float g = gate[b * NN + n];
#pragma unroll
            for (int ct = 0; ct < 2; ct++) {
#pragma unroll
                for (int r = 0; r < 16; r++) {
                    int c = cB + ct * 32 + (r & 3) + 8 * (r >> 2) + 4 * l5;
                    vbf[((size_t)b * CC + c) * NN + np] = f2bf((acc[ct][nh2][r] + bv[c]) * g);
                }
            }
        }
    }
}

// ---------------------------------------------------------------- stats ---
// 256 blocks x 8 waves (strip=w&1, ns=w>>1). Swapped energy (lane=m), lse in
// log2 domain, per-lane scalar stats. K packed direct from global.
__global__ __launch_bounds__(512, 4) void stats_kernel(
    const u16* __restrict__ qpk, const u16* __restrict__ kpk,
    float* __restrict__ lse)
{
    __shared__ float Sm[8][32], Ss[8][32];
    int bid = blockIdx.x;
    int b  = (bid >> 1) & 3;
    int mt = (bid >> 3) | ((bid & 1) << 5);
    int tid = threadIdx.x;
    int w = tid >> 6, l = tid & 63;
    int l5 = l >> 5, l31 = l & 31;
    int strip = w & 1, ns = w >> 1;
    int mS = mt * 64 + strip * 32;

    size_t qo = ((size_t)b * NN + mS + l31) * 64 + 8 * l5;
    s16x8 qh0 = *(const s16x8*)(qpk + qo),      ql0 = *(const s16x8*)(qpk + qo + 32);
    s16x8 qh1 = *(const s16x8*)(qpk + qo + 16), ql1 = *(const s16x8*)(qpk + qo + 48);

    float rmax = -1e30f, rsum = 0.f;

    for (int it = 0; it < 32; it++) {
        size_t ko = ((size_t)b * NN + it * 128 + ns * 32 + l31) * 64 + 8 * l5;
        s16x8 kh0 = *(const s16x8*)(kpk + ko),      kl0 = *(const s16x8*)(kpk + ko + 32);
        s16x8 kh1 = *(const s16x8*)(kpk + ko + 16), kl1 = *(const s16x8*)(kpk + ko + 48);
        f32x16 a = ZERO16;
        a = __builtin_amdgcn_mfma_f32_32x32x16_bf16(kh0, ql0, a, 0, 0, 0);
        a = __builtin_amdgcn_mfma_f32_32x32x16_bf16(kl0, qh0, a, 0, 0, 0);
        a = __builtin_amdgcn_mfma_f32_32x32x16_bf16(kh0, qh0, a, 0, 0, 0);
        a = __builtin_amdgcn_mfma_f32_32x32x16_bf16(kh1, ql1, a, 0, 0, 0);
        a = __builtin_amdgcn_mfma_f32_32x32x16_bf16(kl1, qh1, a, 0, 0, 0);
        a = __builtin_amdgcn_mfma_f32_32x32x16_bf16(kh1, qh1, a, 0, 0, 0);
        float t0 = fmaxf(fmaxf(a[0], a[1]),   fmaxf(a[2], a[3]));
        float t1 = fmaxf(fmaxf(a[4], a[5]),   fmaxf(a[6], a[7]));
        float t2 = fmaxf(fmaxf(a[8], a[9]),   fmaxf(a[10], a[11]));
        float t3 = fmaxf(fmaxf(a[12], a[13]), fmaxf(a[14], a[15]));
        float tm = fmaxf(fmaxf(t0, t1), fmaxf(t2, t3));
        float nm = fmaxf(rmax, tm);
        float add = 0.f;
#pragma unroll
        for (int r = 0; r < 16; r++) add += exp2f(a[r] - nm);
        rsum = rsum * exp2f(rmax - nm) + add;
        rmax = nm;
    }

    {
        float om = __shfl_xor(rmax, 32);
        float os = __shfl_xor(rsum, 32);
        float nm = fmaxf(rmax, om);
        rsum = rsum * exp2f(rmax - nm) + os * exp2f(om - nm);
        rmax = nm;
    }
    if (l < 32) { Sm[w][l] = rmax; Ss[w][l] = rsum; }
    __syncthreads();
    if (tid < 64) {
        int ww = tid >> 5;
        int mm = tid & 31;
        float M = -1e30f;
#pragma unroll
        for (int j = 0; j < 4; j++) M = fmaxf(M, Sm[ww + 2 * j][mm]);
        float S = 0.f;
#pragma unroll
        for (int j = 0; j < 4; j++)
            S += Ss[ww + 2 * j][mm] * exp2f(Sm[ww + 2 * j][mm] - M);
        lse[b * NN + mt * 64 + ww * 32 + mm] = M + log2f(S);
    }
}

// ---------------------------------------------------------------- out -----
// 256 blocks: sub=bid&7 -> b=sub&3, mt-parity=sub>>2 (XCD pins (b,parity)).
// Block = 64 m x 256 c, n-tile 128, LDS 128 KB (V dbuf), 1 block/CU.
// 8 waves = (strip=w&1, ns=w>>1). ORDER MATTERS: K(it+1) fragment loads are
// issued BEFORE STAGE(it+1), and energy(it) uses K regs prefetched last iter
// -> no vmcnt drain before compute; the only vmcnt(0) is folded into the
// end-of-iter barrier, hidden under ~1.5K cycles of MFMA/exp2/ds_read.
__global__ __launch_bounds__(512, 2) void out_kernel(
    const u16* __restrict__ qpk, const u16* __restrict__ kpk,
    const u16* __restrict__ vbf, const float* __restrict__ lse,
    const float* __restrict__ x, const float* __restrict__ gamma,
    float* __restrict__ out)
{
    __shared__ u16 Vl[2][256 * 128];   // 2 x 64 KB [c][n_logical] swizzled
    int bid = blockIdx.x;
    int sub = bid & 7;
    int b  = sub & 3;
    int mt = (bid >> 3) + 32 * (sub >> 2);
    int tid = threadIdx.x;
    int w = tid >> 6, l = tid & 63;
    int l5 = l >> 5, l31 = l & 31;
    int strip = w & 1, ns = w >> 1;
    int mS = mt * 64 + strip * 32;

    size_t qo = ((size_t)b * NN + mS + l31) * 64 + 8 * l5;
    s16x8 qh0 = *(const s16x8*)(qpk + qo),      ql0 = *(const s16x8*)(qpk + qo + 32);
    s16x8 qh1 = *(const s16x8*)(qpk + qo + 16), ql1 = *(const s16x8*)(qpk + qo + 48);

    float lse_m = lse[b * NN + mS + l31];

    f32x16 acc[8] = {ZERO16, ZERO16, ZERO16, ZERO16,
                     ZERO16, ZERO16, ZERO16, ZERO16};
    const u16* vb = vbf + (size_t)b * CC * NN;
    size_t kbase = ((size_t)b * NN + ns * 32 + l31) * 64 + 8 * l5;

    // stage full V tile (256c x 128n = 64 KB): 8 x gload_lds16 per thread
#define STAGE(buf, it)                                                        \
    {                                                                         \
        int n0s = (it) * 128;                                                 \
        _Pragma("unroll")                                                     \
        for (int j = 0; j < 8; j++) {                                         \
            int s = j * 512 + w * 64 + l;                                     \
            int c = s >> 4, chk = s & 15;                                     \
            const u16* src = vb + (size_t)c * NN + n0s +                      \
                             ((chk * 8) ^ ((c & 15) << 3));                   \
            GLOAD_LDS16(src, &Vl[buf][(j * 512 + w * 64) * 8]);               \
        }                                                                     \
    }

    // prologue: K(0) into regs FIRST, then V DMA
    s16x8 kh0c, kl0c, kh1c, kl1c;
    {
        size_t ko = kbase;
        kh0c = *(const s16x8*)(kpk + ko);      kl0c = *(const s16x8*)(kpk + ko + 32);
        kh1c = *(const s16x8*)(kpk + ko + 16); kl1c = *(const s16x8*)(kpk + ko + 48);
    }
    STAGE(0, 0);
    __syncthreads();

    for (int it = 0; it < 32; it++) {
        // ---- prefetch K(it+1) regs, THEN issue STAGE(it+1)
        int itn = (it < 31) ? (it + 1) : 31;
        size_t ko = kbase + (size_t)itn * 128 * 64;
        s16x8 kh0n = *(const s16x8*)(kpk + ko);
        s16x8 kl0n = *(const s16x8*)(kpk + ko + 32);
        s16x8 kh1n = *(const s16x8*)(kpk + ko + 16);
        s16x8 kl1n = *(const s16x8*)(kpk + ko + 48);
        if (it < 31) STAGE((it + 1) & 1, it + 1);

        // ---- ENERGY: uses K regs from previous iteration (no vm wait)
        f32x16 a = ZERO16;
        a = __builtin_amdgcn_mfma_f32_32x32x16_bf16(kh0c, ql0, a, 0, 0, 0);
        a = __builtin_amdgcn_mfma_f32_32x32x16_bf16(kl0c, qh0, a, 0, 0, 0);
        a = __builtin_amdgcn_mfma_f32_32x32x16_bf16(kh0c, qh0, a, 0, 0, 0);
        a = __builtin_amdgcn_mfma_f32_32x32x16_bf16(kh1c, ql1, a, 0, 0, 0);
        a = __builtin_amdgcn_mfma_f32_32x32x16_bf16(kl1c, qh1, a, 0, 0, 0);
        a = __builtin_amdgcn_mfma_f32_32x32x16_bf16(kh1c, qh1, a, 0, 0, 0);

        // ---- P in registers: exp2 + cvt_pk of CONSECUTIVE regs
        union { u32 w4[4]; s16x8 v; } pa0, pa1;
        pa0.w4[0] = cvtpk_bf16(exp2f(a[0]  - lse_m), exp2f(a[1]  - lse_m));
        pa0.w4[1] = cvtpk_bf16(exp2f(a[2]  - lse_m), exp2f(a[3]  - lse_m));
        pa0.w4[2] = cvtpk_bf16(exp2f(a[4]  - lse_m), exp2f(a[5]  - lse_m));
        pa0.w4[3] = cvtpk_bf16(exp2f(a[6]  - lse_m), exp2f(a[7]  - lse_m));
        pa1.w4[0] = cvtpk_bf16(exp2f(a[8]  - lse_m), exp2f(a[9]  - lse_m));
        pa1.w4[1] = cvtpk_bf16(exp2f(a[10] - lse_m), exp2f(a[11] - lse_m));
        pa1.w4[2] = cvtpk_bf16(exp2f(a[12] - lse_m), exp2f(a[13] - lse_m));
        pa1.w4[3] = cvtpk_bf16(exp2f(a[14] - lse_m), exp2f(a[15] - lse_m));

        // ---- PV: window (32 n) x 256 c from LDS V (conflict-free swizzle)
        const u16* Vb = Vl[it & 1];
#pragma unroll
        for (int cs = 0; cs < 8; cs++) {
            int c = cs * 32 + l31;
            int rb = c * 128;
            int sw = (c & 15) << 3;
            s16x8 vv0 = *(const s16x8*)(Vb + rb + ((ns * 32 + 8 * l5) ^ sw));
            s16x8 vv1 = *(const s16x8*)(Vb + rb + ((ns * 32 + 16 + 8 * l5) ^ sw));
            acc[cs] = __builtin_amdgcn_mfma_f32_32x32x16_bf16(pa0.v, vv0, acc[cs], 0, 0, 0);
            acc[cs] = __builtin_amdgcn_mfma_f32_32x32x16_bf16(pa1.v, vv1, acc[cs], 0, 0, 0);
        }
        __syncthreads();

        kh0c = kh0n; kl0c = kl0n; kh1c = kh1n; kl1c = kl1n;
    }

    // ---- epilogue: reduce ns-partials (4 per output), 4 passes of 2 cs.
    // Pitch-33 layout: bank = (33*row + col) % 32 = (row + col) % 32 -> CF.
    float gm = gamma[0];
    float* red = (float*)&Vl[0][0];
    int row = w * 64 + l;
#pragma unroll
    for (int p = 0; p < 4; p++) {
        int cs0 = 2 * p;
#pragma unroll
        for (int q = 0; q < 4; q++) {
            float4 v4;
            v4.x = acc[cs0][4 * q + 0]; v4.y = acc[cs0][4 * q + 1];
            v4.z = acc[cs0][4 * q + 2]; v4.w = acc[cs0][4 * q + 3];
            *(float4*)(red + row * 33 + 4 * q) = v4;
            float4 w4;
            w4.x = acc[cs0 + 1][4 * q + 0]; w4.y = acc[cs0 + 1][4 * q + 1];
            w4.z = acc[cs0 + 1][4 * q + 2]; w4.w = acc[cs0 + 1][4 * q + 3];
            *(float4*)(red + row * 33 + 16 + 4 * q) = w4;
        }
        __syncthreads();
        int strip_o = w & 1, csi = (w >> 1) & 1, eh = w >> 2;
        int c = (cs0 + csi) * 32 + l31;
#pragma unroll
        for (int t = 0; t < 2; t++) {
            int ebase = eh * 8 + 4 * t;
            float4 s = {0.f, 0.f, 0.f, 0.f};
#pragma unroll
            for (int j = 0; j < 4; j++) {
                float4 v = *(const float4*)(red + (size_t)((strip_o + 2 * j) * 64 + l) * 33
                                            + csi * 16 + ebase);
                s.x += v.x; s.y += v.y; s.z += v.z; s.w += v.w;
            }
            int m = mt * 64 + strip_o * 32 + 8 * (eh * 2 + t) + 4 * l5;
            size_t o = ((size_t)b * CC + c) * NN + m;
            float4 x4 = *(const float4*)(x + o);
            float4 r4;
            r4.x = fmaf(gm, s.x, x4.x);
            r4.y = fmaf(gm, s.y, x4.y);
            r4.z = fmaf(gm, s.z, x4.z);
            r4.w = fmaf(gm, s.w, x4.w);
            *(float4*)(out + o) = r4;
        }
        __syncthreads();
    }
#undef STAGE
}

// ---------------------------------------------------------------- launch --
extern "C" void kernel_launch(void* const* d_in, const int* in_sizes, int n_in,
                              void* d_out, int out_size, void* d_ws, size_t ws_size,
                              hipStream_t stream)
{
    const float* x     = (const float*)d_in[0];
    const float* g0    = (const float*)d_in[1];
    const float* Wq    = (const float*)d_in[2];
    const float* bq    = (const float*)d_in[3];
    const float* Wk    = (const float*)d_in[4];
    const float* bk    = (const float*)d_in[5];
    const float* Wv    = (const float*)d_in[6];
    const float* bv    = (const float*)d_in[7];
    const float* gamma = (const float*)d_in[8];
    float* out = (float*)d_out;

    char* p = (char*)d_ws;
    u16* qpk = (u16*)p; p += (size_t)4 * NN * 64 * 2;   // 2 MB packed [n][hi|lo]
    u16* kpk = (u16*)p; p += (size_t)4 * NN * 64 * 2;   // 2 MB
    u16* vbf = (u16*)p; p += (size_t)4 * CC * NN * 2;   // 8 MB, n-interleaved
    float* gate = (float*)p; p += (size_t)4 * NN * 4;
    float* lse  = (float*)p; p += (size_t)4 * NN * 4;
    u16* wqhi = (u16*)p; p += 8192 * 2;
    u16* wqlo = (u16*)p; p += 8192 * 2;
    u16* wkhi = (u16*)p; p += 8192 * 2;
    u16* wklo = (u16*)p; p += 8192 * 2;
    u16* wvbf = (u16*)p; p += 65536 * 2;

    hipLaunchKernelGGL(gate_kernel, dim3(64), dim3(256), 0, stream,
                       g0, Wq, Wk, Wv, gate, wqhi, wqlo, wkhi, wklo, wvbf);
    hipLaunchKernelGGL(qkv_kernel, dim3(256), dim3(512), 0, stream,
                       x, wqhi, wqlo, wkhi, wklo, wvbf, bq, bk, bv, gate,
                       qpk, kpk, vbf);
    hipLaunchKernelGGL(stats_kernel, dim3(256), dim3(512), 0, stream,
                       qpk, kpk, lse);
    hipLaunchKernelGGL(out_kernel, dim3(256), dim3(512), 0, stream,
                       qpk, kpk, vbf, lse, x, gamma, out);
}